// Round 4
// baseline (16924.802 us; speedup 1.0000x reference)
//
#include <hip/hip_runtime.h>

#define T_STEPS 512
#define BATCH   64
#define CIN     512
#define CH      1024

typedef __attribute__((ext_vector_type(8))) short bf16x8;
typedef __attribute__((ext_vector_type(4))) float f32x4;
typedef unsigned long long ull;

__device__ __forceinline__ unsigned short f2bf(float f) {
  unsigned int x = __float_as_uint(f);
  x += 0x7fffu + ((x >> 16) & 1u);   // RNE
  return (unsigned short)(x >> 16);
}
__device__ __forceinline__ float bf2f(unsigned short u) {
  return __uint_as_float(((unsigned int)u) << 16);
}

// ---------------------------------------------------------------------------
// fp32 [R][C] -> bf16 hi/lo transpose+split.
// ilv=0: separate arrays oh/ol, layout [C][R]   (used for Wx)
// ilv=1: single array oh, layout [C][R/8][hi8|lo8] 16-short units (used for Wh)
// ---------------------------------------------------------------------------
__global__ __launch_bounds__(256) void transpose_cvt_split(
    const float* __restrict__ in, unsigned short* __restrict__ oh,
    unsigned short* __restrict__ ol, int R, int Cc, int ilv)
{
  __shared__ float tile[32][33];
  const int tx = threadIdx.x & 31, ty = threadIdx.x >> 5;
  const int bx = blockIdx.x * 32;  // C offset
  const int by = blockIdx.y * 32;  // R offset
#pragma unroll
  for (int i = 0; i < 32; i += 8)
    tile[ty + i][tx] = in[(size_t)(by + ty + i) * Cc + bx + tx];
  __syncthreads();
#pragma unroll
  for (int i = 0; i < 32; i += 8) {
    float w = tile[tx][ty + i];
    unsigned short hi = f2bf(w);
    unsigned short lo = f2bf(w - bf2f(hi));
    size_t col = (size_t)(bx + ty + i);
    size_t k = (size_t)(by + tx);
    if (ilv) {
      size_t base = (col * (size_t)(R >> 3) + (k >> 3)) * 16 + (k & 7);
      oh[base] = hi;
      oh[base + 8] = lo;
    } else {
      size_t o = col * R + k;
      oh[o] = hi;
      ol[o] = lo;
    }
  }
}

// ---------------------------------------------------------------------------
// fp32 -> bf16 elementwise (h0 = state).
// ---------------------------------------------------------------------------
__global__ void cvt_f32_bf16(const float* __restrict__ in,
                             unsigned short* __restrict__ outp, int n)
{
  int i = (blockIdx.x * blockDim.x + threadIdx.x) * 4;
  if (i < n) {
    float4 v = *(const float4*)(in + i);
    ushort4 o;
    o.x = f2bf(v.x); o.y = f2bf(v.y); o.z = f2bf(v.z); o.w = f2bf(v.w);
    *(ushort4*)(outp + i) = o;
  }
}

// ---------------------------------------------------------------------------
// xp = inputs @ Wx + b, COMPENSATED bf16 GEMM -> fp32 output. (unchanged)
// ---------------------------------------------------------------------------
#define BM 128
#define BN 128
#define BK 32

__global__ __launch_bounds__(256) void gemm_xp(
    const float* __restrict__ A,
    const unsigned short* __restrict__ BTh,
    const unsigned short* __restrict__ BTl,
    const float* __restrict__ bias,
    float* __restrict__ C)                  // [32768][1024] f32 (out[1] region)
{
  __shared__ unsigned short Ah[BM][BK + 8];
  __shared__ unsigned short Al[BM][BK + 8];
  __shared__ unsigned short Bh[BN][BK + 8];
  __shared__ unsigned short Bl[BN][BK + 8];
  const int tid = threadIdx.x;
  const int w = tid >> 6, l = tid & 63;
  const int wm = (w >> 1) * 64, wn = (w & 1) * 64;
  const int q = l >> 4, m = l & 15;
  const int row0 = blockIdx.y * BM;
  const int col0 = blockIdx.x * BN;
  f32x4 acc[4][4];
#pragma unroll
  for (int i = 0; i < 4; i++)
#pragma unroll
    for (int j = 0; j < 4; j++) acc[i][j] = (f32x4){0.f, 0.f, 0.f, 0.f};

  for (int kt = 0; kt < CIN; kt += BK) {
#pragma unroll
    for (int i = 0; i < 4; i++) {
      int cid = tid + i * 256;
      int r = cid >> 3, c4 = cid & 7;
      float4 v = *(const float4*)(A + (size_t)(row0 + r) * CIN + kt + c4 * 4);
      ushort4 hi, lo;
      hi.x = f2bf(v.x); lo.x = f2bf(v.x - bf2f(hi.x));
      hi.y = f2bf(v.y); lo.y = f2bf(v.y - bf2f(hi.y));
      hi.z = f2bf(v.z); lo.z = f2bf(v.z - bf2f(hi.z));
      hi.w = f2bf(v.w); lo.w = f2bf(v.w - bf2f(hi.w));
      *(ushort4*)(&Ah[r][c4 * 4]) = hi;
      *(ushort4*)(&Al[r][c4 * 4]) = lo;
    }
#pragma unroll
    for (int i = 0; i < 4; i++) {
      int cid = tid + i * 256;
      const unsigned short* src = (cid < 512) ? BTh : BTl;
      unsigned short (*dst)[BK + 8] = (cid < 512) ? Bh : Bl;
      int rem = cid & 511;
      int r = rem >> 2, c8 = rem & 3;
      uint4 u = *(const uint4*)(src + (size_t)(col0 + r) * CIN + kt + c8 * 8);
      *(uint4*)(&dst[r][c8 * 8]) = u;
    }
    __syncthreads();
    bf16x8 ah[4], al[4], bh[4], bl[4];
#pragma unroll
    for (int i = 0; i < 4; i++) {
      ah[i] = *(const bf16x8*)(&Ah[wm + i * 16 + m][q * 8]);
      al[i] = *(const bf16x8*)(&Al[wm + i * 16 + m][q * 8]);
    }
#pragma unroll
    for (int j = 0; j < 4; j++) {
      bh[j] = *(const bf16x8*)(&Bh[wn + j * 16 + m][q * 8]);
      bl[j] = *(const bf16x8*)(&Bl[wn + j * 16 + m][q * 8]);
    }
#pragma unroll
    for (int i = 0; i < 4; i++)
#pragma unroll
      for (int j = 0; j < 4; j++) {
        acc[i][j] = __builtin_amdgcn_mfma_f32_16x16x32_bf16(ah[i], bh[j], acc[i][j], 0, 0, 0);
        acc[i][j] = __builtin_amdgcn_mfma_f32_16x16x32_bf16(ah[i], bl[j], acc[i][j], 0, 0, 0);
        acc[i][j] = __builtin_amdgcn_mfma_f32_16x16x32_bf16(al[i], bh[j], acc[i][j], 0, 0, 0);
      }
    __syncthreads();
  }
#pragma unroll
  for (int i = 0; i < 4; i++) {
#pragma unroll
    for (int j = 0; j < 4; j++) {
      int col = col0 + wn + j * 16 + m;
      float bv = bias[col];
#pragma unroll
      for (int r = 0; r < 4; r++) {
        int row = row0 + wm + i * 16 + q * 4 + r;
        C[(size_t)row * CH + col] = acc[i][j][r] + bv;
      }
    }
  }
}

// ---------------------------------------------------------------------------
// Persistent scan: h_{t+1} = tanh(xp_t + h_t @ Wh), 512 steps.
// 16 WGs x 1024 threads; WG owns 64 cols.
//
// Barrier v2 (this round's change): CONTENTION-FREE signaling.
//  - 16 per-WG slots, 128B apart. Signal = ONE relaxed agent-scope STORE
//    of (t+1) to own slot (no RMW chain on a hot line; R0-R3 used a single
//    fetch_add counter -> 16 serialized line-ownership transfers per step).
//  - All waves poll in parallel: lane l loads slot[l&15]; exit on
//    __all(v >= t+1). No tid0 poll, no release __syncthreads.
//  - Safety unchanged: signal issued only after vmcnt(0)+sync of all h
//    stores; poll includes own slot so no wave overruns its own WG.
// ---------------------------------------------------------------------------
__global__ __launch_bounds__(1024) void rnn_scan(
    const unsigned short* __restrict__ WhTi, // [1024 cols][128][hi8|lo8] bf16
    float* __restrict__ xpf,                 // [512*64*1024] f32 (= out[1])
    unsigned short* __restrict__ h0,
    unsigned short* __restrict__ h1,
    float* __restrict__ out,                 // out[0] region
    int* __restrict__ slots)                 // 16 x 32-int (128B) slots
{
  __shared__ unsigned short hS[65536];              // 128 KB staged h
  __shared__ __align__(8) unsigned short hX[64 * 76]; // 9.5 KB transpose buf
  const int tid = threadIdx.x;
  const int w = tid >> 6, l = tid & 63;
  const int mt = w & 3, nt = w >> 2;
  const int col0 = blockIdx.x * 64;
  const int q = l >> 4, m = l & 15;
  const int colg = col0 + nt * 16 + m;
  const int arow = mt * 16 + m;
  const int myslot = (l & 15) * 32;

  // xp prefetch for t=0 (own slice; gemm_xp output, inter-kernel coherent)
  float xp[4];
#pragma unroll
  for (int r = 0; r < 4; r++) {
    int brow = mt * 16 + q * 4 + r;
    xp[r] = xpf[(size_t)brow * CH + colg];
  }

  for (int t = 0; t < T_STEPS; t++) {
    const unsigned short* hsrc = (t & 1) ? h1 : h0;
    unsigned short* hdst = (t & 1) ? h0 : h1;

    // ---- stage all of h: 16 x 8B bypass loads issued up-front ----
    ull hv[16];
#pragma unroll
    for (int i = 0; i < 16; i++) {
      int cid = i * 1024 + tid;            // 16384 8B-units: [64 rows][256]
      int r = cid >> 8, e = cid & 255;
      hv[i] = __hip_atomic_load((const ull*)(hsrc + (size_t)r * 1024 + e * 4),
                                __ATOMIC_RELAXED, __HIP_MEMORY_SCOPE_AGENT);
    }
#pragma unroll
    for (int i = 0; i < 16; i++) {
      int cid = i * 1024 + tid;
      int r = cid >> 8, e = cid & 255;
      int u16 = e >> 1, sub = e & 1;       // 16B unit, XOR swizzle in 8-groups
      *(ull*)((char*)hS + r * 2048 + ((u16 ^ (r & 7)) * 16) + sub * 8) = hv[i];
    }
    __syncthreads();                       // S1

    // ---- MFMA: 32 k-groups, weights hi/lo interleaved 32B per lane ----
    f32x4 acc = {0.f, 0.f, 0.f, 0.f};
#pragma unroll 4
    for (int kk = 0; kk < 32; kk++) {
      int cl = kk * 4 + q;                 // 16B-unit index 0..127 (= k/8)
      bf16x8 af = *(const bf16x8*)((const char*)hS + arow * 2048 +
                                   ((cl ^ (arow & 7)) * 16));
      const unsigned short* wp = WhTi + ((size_t)colg * 128 + cl) * 16;
      bf16x8 bh = *(const bf16x8*)(wp);
      bf16x8 bl = *(const bf16x8*)(wp + 8);
      acc = __builtin_amdgcn_mfma_f32_16x16x32_bf16(af, bh, acc, 0, 0, 0);
      acc = __builtin_amdgcn_mfma_f32_16x16x32_bf16(af, bl, acc, 0, 0, 0);
    }
    __syncthreads();                       // S2 (hS reads done)

    // ---- epilogue: tanh, transpose in LDS for coalesced h-store ----
    size_t tbase = (size_t)t * (BATCH * CH);
    float hv4[4];
#pragma unroll
    for (int r = 0; r < 4; r++) {
      int brow = mt * 16 + q * 4 + r;
      float pre = acc[r] + xp[r];
      // fast tanh: 1 - 2/(e^{2x}+1); saturates correctly at +/-inf
      float e2 = __expf(2.f * pre);
      float hvf = 1.f - 2.f / (e2 + 1.f);
      hv4[r] = hvf;
      hX[brow * 76 + nt * 16 + m] = f2bf(hvf);
    }
    __syncthreads();                       // S3
    {
      int rrow = tid >> 4, ch = tid & 15;  // 64 rows x 16 8B-chunks
      ull v8 = *(const ull*)(&hX[rrow * 76 + ch * 4]);
      __hip_atomic_store((ull*)(hdst + (size_t)rrow * 1024 + col0 + ch * 4), v8,
                         __ATOMIC_RELAXED, __HIP_MEMORY_SCOPE_AGENT);
    }
    asm volatile("s_waitcnt vmcnt(0)" ::: "memory");  // drain h-stores
    __syncthreads();                       // S4 (whole WG's h at coherence pt)

    if (tid == 0)                          // contention-free signal: own slot
      __hip_atomic_store(&slots[blockIdx.x * 32], t + 1,
                         __ATOMIC_RELAXED, __HIP_MEMORY_SCOPE_AGENT);

    // shadow work: out/xpf stores + next-step xp prefetch overlap the poll
#pragma unroll
    for (int r = 0; r < 4; r++) {
      int brow = mt * 16 + q * 4 + r;
      size_t off = tbase + (size_t)brow * CH + colg;
      out[off] = hv4[r];
      xpf[off] = hv4[r];
    }
    if (t + 1 < T_STEPS) {
#pragma unroll
      for (int r = 0; r < 4; r++) {
        int brow = mt * 16 + q * 4 + r;
        xp[r] = xpf[tbase + (size_t)(BATCH * CH) + (size_t)brow * CH + colg];
      }
    }

    // all-wave parallel poll: lanes cover the 16 slots, 4x redundancy
    {
      const int target = t + 1;
      while (true) {
        int v = __hip_atomic_load(&slots[myslot], __ATOMIC_RELAXED,
                                  __HIP_MEMORY_SCOPE_AGENT);
        if (__all(v >= target)) break;
      }
    }
    // no release barrier needed: each wave proceeds independently; hS/hX
    // hazards are covered by S2/S4 + own-slot inclusion in the poll.
  }
}

// ---------------------------------------------------------------------------
extern "C" void kernel_launch(void* const* d_in, const int* in_sizes, int n_in,
                              void* d_out, int out_size, void* d_ws, size_t ws_size,
                              hipStream_t stream)
{
  const float* inputs = (const float*)d_in[0];  // [512,64,512]
  const float* state  = (const float*)d_in[1];  // [1,64,1024]
  const float* Wx     = (const float*)d_in[2];  // [512,1024]
  const float* Wh     = (const float*)d_in[3];  // [1024,1024]
  const float* bias   = (const float*)d_in[4];  // [1024]
  float* out = (float*)d_out;
  float* xpf = out + (size_t)T_STEPS * BATCH * CH;  // out[1] region = xp scratch

  char* ws = (char*)d_ws;
  size_t off = 0;
  unsigned short* WxTh = (unsigned short*)(ws + off); off += (size_t)CH * CIN * 2;  // 1 MB
  unsigned short* WxTl = (unsigned short*)(ws + off); off += (size_t)CH * CIN * 2;  // 1 MB
  unsigned short* WhTi = (unsigned short*)(ws + off); off += (size_t)CH * CH * 4;   // 4 MB interleaved
  unsigned short* h0   = (unsigned short*)(ws + off); off += (size_t)BATCH * CH * 2;
  unsigned short* h1   = (unsigned short*)(ws + off); off += (size_t)BATCH * CH * 2;
  int* slots           = (int*)(ws + off);            off += 16 * 32 * sizeof(int);

  hipMemsetAsync(slots, 0, 16 * 32 * sizeof(int), stream);
  hipLaunchKernelGGL(transpose_cvt_split, dim3(CH / 32, CIN / 32), dim3(256), 0, stream,
                     Wx, WxTh, WxTl, CIN, CH, 0);
  hipLaunchKernelGGL(transpose_cvt_split, dim3(CH / 32, CH / 32), dim3(256), 0, stream,
                     Wh, WhTi, (unsigned short*)nullptr, CH, CH, 1);
  hipLaunchKernelGGL(cvt_f32_bf16, dim3((BATCH * CH / 4) / 256), dim3(256), 0, stream,
                     state, h0, BATCH * CH);
  hipLaunchKernelGGL(gemm_xp, dim3(CH / BN, (T_STEPS * BATCH) / BM), dim3(256), 0, stream,
                     inputs, WxTh, WxTl, bias, xpf);
  hipLaunchKernelGGL(rnn_scan, dim3(16), dim3(1024), 0, stream,
                     WhTi, xpf, h0, h1, out, slots);
}

// Round 5
// 5959.566 us; speedup vs baseline: 2.8399x; 2.8399x over previous
//
#include <hip/hip_runtime.h>

#define T_STEPS 512
#define BATCH   64
#define CIN     512
#define CH      1024
#define NWG     64   // rnn_scan workgroups; CH/NWG cols each

typedef __attribute__((ext_vector_type(8))) short bf16x8;
typedef __attribute__((ext_vector_type(4))) float f32x4;
typedef unsigned long long ull;

__device__ __forceinline__ unsigned short f2bf(float f) {
  unsigned int x = __float_as_uint(f);
  x += 0x7fffu + ((x >> 16) & 1u);   // RNE
  return (unsigned short)(x >> 16);
}
__device__ __forceinline__ float bf2f(unsigned short u) {
  return __uint_as_float(((unsigned int)u) << 16);
}

// ---------------------------------------------------------------------------
// fp32 [R][C] -> bf16 hi/lo transpose+split.
// ilv=0: separate arrays oh/ol, layout [C][R]   (used for Wx)
// ilv=1: single array oh, layout [C][R/8][hi8|lo8] 16-short units (used for Wh)
// ---------------------------------------------------------------------------
__global__ __launch_bounds__(256) void transpose_cvt_split(
    const float* __restrict__ in, unsigned short* __restrict__ oh,
    unsigned short* __restrict__ ol, int R, int Cc, int ilv)
{
  __shared__ float tile[32][33];
  const int tx = threadIdx.x & 31, ty = threadIdx.x >> 5;
  const int bx = blockIdx.x * 32;  // C offset
  const int by = blockIdx.y * 32;  // R offset
#pragma unroll
  for (int i = 0; i < 32; i += 8)
    tile[ty + i][tx] = in[(size_t)(by + ty + i) * Cc + bx + tx];
  __syncthreads();
#pragma unroll
  for (int i = 0; i < 32; i += 8) {
    float w = tile[tx][ty + i];
    unsigned short hi = f2bf(w);
    unsigned short lo = f2bf(w - bf2f(hi));
    size_t col = (size_t)(bx + ty + i);
    size_t k = (size_t)(by + tx);
    if (ilv) {
      size_t base = (col * (size_t)(R >> 3) + (k >> 3)) * 16 + (k & 7);
      oh[base] = hi;
      oh[base + 8] = lo;
    } else {
      size_t o = col * R + k;
      oh[o] = hi;
      ol[o] = lo;
    }
  }
}

// ---------------------------------------------------------------------------
// fp32 -> bf16 elementwise (h0 = state).
// ---------------------------------------------------------------------------
__global__ void cvt_f32_bf16(const float* __restrict__ in,
                             unsigned short* __restrict__ outp, int n)
{
  int i = (blockIdx.x * blockDim.x + threadIdx.x) * 4;
  if (i < n) {
    float4 v = *(const float4*)(in + i);
    ushort4 o;
    o.x = f2bf(v.x); o.y = f2bf(v.y); o.z = f2bf(v.z); o.w = f2bf(v.w);
    *(ushort4*)(outp + i) = o;
  }
}

// ---------------------------------------------------------------------------
// xp = inputs @ Wx + b, COMPENSATED bf16 GEMM -> fp32 output. (unchanged)
// ---------------------------------------------------------------------------
#define BM 128
#define BN 128
#define BK 32

__global__ __launch_bounds__(256) void gemm_xp(
    const float* __restrict__ A,
    const unsigned short* __restrict__ BTh,
    const unsigned short* __restrict__ BTl,
    const float* __restrict__ bias,
    float* __restrict__ C)                  // [32768][1024] f32 (out[1] region)
{
  __shared__ unsigned short Ah[BM][BK + 8];
  __shared__ unsigned short Al[BM][BK + 8];
  __shared__ unsigned short Bh[BN][BK + 8];
  __shared__ unsigned short Bl[BN][BK + 8];
  const int tid = threadIdx.x;
  const int w = tid >> 6, l = tid & 63;
  const int wm = (w >> 1) * 64, wn = (w & 1) * 64;
  const int q = l >> 4, m = l & 15;
  const int row0 = blockIdx.y * BM;
  const int col0 = blockIdx.x * BN;
  f32x4 acc[4][4];
#pragma unroll
  for (int i = 0; i < 4; i++)
#pragma unroll
    for (int j = 0; j < 4; j++) acc[i][j] = (f32x4){0.f, 0.f, 0.f, 0.f};

  for (int kt = 0; kt < CIN; kt += BK) {
#pragma unroll
    for (int i = 0; i < 4; i++) {
      int cid = tid + i * 256;
      int r = cid >> 3, c4 = cid & 7;
      float4 v = *(const float4*)(A + (size_t)(row0 + r) * CIN + kt + c4 * 4);
      ushort4 hi, lo;
      hi.x = f2bf(v.x); lo.x = f2bf(v.x - bf2f(hi.x));
      hi.y = f2bf(v.y); lo.y = f2bf(v.y - bf2f(hi.y));
      hi.z = f2bf(v.z); lo.z = f2bf(v.z - bf2f(hi.z));
      hi.w = f2bf(v.w); lo.w = f2bf(v.w - bf2f(hi.w));
      *(ushort4*)(&Ah[r][c4 * 4]) = hi;
      *(ushort4*)(&Al[r][c4 * 4]) = lo;
    }
#pragma unroll
    for (int i = 0; i < 4; i++) {
      int cid = tid + i * 256;
      const unsigned short* src = (cid < 512) ? BTh : BTl;
      unsigned short (*dst)[BK + 8] = (cid < 512) ? Bh : Bl;
      int rem = cid & 511;
      int r = rem >> 2, c8 = rem & 3;
      uint4 u = *(const uint4*)(src + (size_t)(col0 + r) * CIN + kt + c8 * 8);
      *(uint4*)(&dst[r][c8 * 8]) = u;
    }
    __syncthreads();
    bf16x8 ah[4], al[4], bh[4], bl[4];
#pragma unroll
    for (int i = 0; i < 4; i++) {
      ah[i] = *(const bf16x8*)(&Ah[wm + i * 16 + m][q * 8]);
      al[i] = *(const bf16x8*)(&Al[wm + i * 16 + m][q * 8]);
    }
#pragma unroll
    for (int j = 0; j < 4; j++) {
      bh[j] = *(const bf16x8*)(&Bh[wn + j * 16 + m][q * 8]);
      bl[j] = *(const bf16x8*)(&Bl[wn + j * 16 + m][q * 8]);
    }
#pragma unroll
    for (int i = 0; i < 4; i++)
#pragma unroll
      for (int j = 0; j < 4; j++) {
        acc[i][j] = __builtin_amdgcn_mfma_f32_16x16x32_bf16(ah[i], bh[j], acc[i][j], 0, 0, 0);
        acc[i][j] = __builtin_amdgcn_mfma_f32_16x16x32_bf16(ah[i], bl[j], acc[i][j], 0, 0, 0);
        acc[i][j] = __builtin_amdgcn_mfma_f32_16x16x32_bf16(al[i], bh[j], acc[i][j], 0, 0, 0);
      }
    __syncthreads();
  }
#pragma unroll
  for (int i = 0; i < 4; i++) {
#pragma unroll
    for (int j = 0; j < 4; j++) {
      int col = col0 + wn + j * 16 + m;
      float bv = bias[col];
#pragma unroll
      for (int r = 0; r < 4; r++) {
        int row = row0 + wm + i * 16 + q * 4 + r;
        C[(size_t)row * CH + col] = acc[i][j][r] + bv;
      }
    }
  }
}

// ---------------------------------------------------------------------------
// Persistent scan: h_{t+1} = tanh(xp_t + h_t @ Wh), 512 steps.
//
// R5: 64 WGs x 16 cols x 256 threads (4 waves, one 16-row tile each).
//  - Per-CU work /4: 64 KB weight slice/step (L2/L1-resident), 1 wave of
//    MFMAs per SIMD. The R2-R4 plateau tracked per-CU serial work, not
//    sync mechanics; this attacks the dominant modeled term.
//  - 1 WG/CU (133 KB LDS), grid 64 <= 256 CUs: co-residency guaranteed.
//  - Same proven protocol: bypass-load staging -> S1 -> MFMA -> S2 ->
//    epilogue -> transpose -> bypass h-store -> vmcnt(0) -> S4 ->
//    per-WG slot store -> shadow out/xpf/prefetch -> all-lane slot poll.
// ---------------------------------------------------------------------------
__global__ __launch_bounds__(256) void rnn_scan(
    const unsigned short* __restrict__ WhTi, // [1024 cols][128][hi8|lo8] bf16
    float* __restrict__ xpf,                 // [512*64*1024] f32 (= out[1])
    unsigned short* __restrict__ h0,
    unsigned short* __restrict__ h1,
    float* __restrict__ out,                 // out[0] region
    int* __restrict__ slots)                 // NWG x 32-int (128B) slots
{
  __shared__ unsigned short hS[65536];                 // 128 KB staged h
  __shared__ __align__(8) unsigned short hX[64 * 20];  // 2.5 KB transpose buf
  const int tid = threadIdx.x;           // 0..255
  const int w = tid >> 6, l = tid & 63;  // 4 waves
  const int mt = w;                      // wave = 16-row tile
  const int col0 = blockIdx.x * 16;
  const int q = l >> 4, m = l & 15;
  const int colg = col0 + m;
  const int arow = mt * 16 + m;
  const int myslot = l * 32;             // lane l polls WG l's slot

  // xp prefetch for t=0 (own slice; gemm_xp output, inter-kernel coherent)
  float xp[4];
#pragma unroll
  for (int r = 0; r < 4; r++) {
    int brow = mt * 16 + q * 4 + r;
    xp[r] = xpf[(size_t)brow * CH + colg];
  }

  for (int t = 0; t < T_STEPS; t++) {
    const unsigned short* hsrc = (t & 1) ? h1 : h0;
    unsigned short* hdst = (t & 1) ? h0 : h1;

    // ---- stage all of h (64 rows x 2KB): 64 x 8B bypass loads/thread ----
    // row index is compile-time constant per unrolled iter; e = tid.
#pragma unroll
    for (int rr = 0; rr < 2; rr++) {
      ull hv[32];
#pragma unroll
      for (int i = 0; i < 32; i++) {
        int r = rr * 32 + i;
        hv[i] = __hip_atomic_load((const ull*)(hsrc + (size_t)r * 1024 + tid * 4),
                                  __ATOMIC_RELAXED, __HIP_MEMORY_SCOPE_AGENT);
      }
#pragma unroll
      for (int i = 0; i < 32; i++) {
        int r = rr * 32 + i;
        *(ull*)((char*)hS + r * 2048 + (((tid >> 1) ^ (r & 7)) * 16) +
                (tid & 1) * 8) = hv[i];
      }
    }
    __syncthreads();                       // S1

    // ---- MFMA: 32 k-groups, weights hi/lo interleaved 32B per lane ----
    f32x4 acc = {0.f, 0.f, 0.f, 0.f};
#pragma unroll 4
    for (int kk = 0; kk < 32; kk++) {
      int cl = kk * 4 + q;                 // 16B-unit index 0..127 (= k/8)
      bf16x8 af = *(const bf16x8*)((const char*)hS + arow * 2048 +
                                   ((cl ^ (arow & 7)) * 16));
      const unsigned short* wp = WhTi + ((size_t)colg * 128 + cl) * 16;
      bf16x8 bh = *(const bf16x8*)(wp);
      bf16x8 bl = *(const bf16x8*)(wp + 8);
      acc = __builtin_amdgcn_mfma_f32_16x16x32_bf16(af, bh, acc, 0, 0, 0);
      acc = __builtin_amdgcn_mfma_f32_16x16x32_bf16(af, bl, acc, 0, 0, 0);
    }
    __syncthreads();                       // S2 (hS reads done)

    // ---- epilogue: tanh, transpose in LDS for coalesced h-store ----
    size_t tbase = (size_t)t * (BATCH * CH);
    float hv4[4];
#pragma unroll
    for (int r = 0; r < 4; r++) {
      int brow = mt * 16 + q * 4 + r;
      float pre = acc[r] + xp[r];
      // fast tanh: 1 - 2/(e^{2x}+1); saturates correctly at +/-inf
      float e2 = __expf(2.f * pre);
      float hvf = 1.f - 2.f / (e2 + 1.f);
      hv4[r] = hvf;
      hX[brow * 20 + m] = f2bf(hvf);
    }
    __syncthreads();                       // S3
    {
      int rrow = tid >> 2, ch = tid & 3;   // 64 rows x 4 8B-chunks
      ull v8 = *(const ull*)(&hX[rrow * 20 + ch * 4]);
      __hip_atomic_store((ull*)(hdst + (size_t)rrow * 1024 + col0 + ch * 4), v8,
                         __ATOMIC_RELAXED, __HIP_MEMORY_SCOPE_AGENT);
    }
    asm volatile("s_waitcnt vmcnt(0)" ::: "memory");  // drain h-stores
    __syncthreads();                       // S4 (whole WG's h at coherence pt)

    if (tid == 0)                          // contention-free signal: own slot
      __hip_atomic_store(&slots[blockIdx.x * 32], t + 1,
                         __ATOMIC_RELAXED, __HIP_MEMORY_SCOPE_AGENT);

    // shadow work: out/xpf stores + next-step xp prefetch overlap the poll
#pragma unroll
    for (int r = 0; r < 4; r++) {
      int brow = mt * 16 + q * 4 + r;
      size_t off = tbase + (size_t)brow * CH + colg;
      out[off] = hv4[r];
      xpf[off] = hv4[r];
    }
    if (t + 1 < T_STEPS) {
#pragma unroll
      for (int r = 0; r < 4; r++) {
        int brow = mt * 16 + q * 4 + r;
        xp[r] = xpf[tbase + (size_t)(BATCH * CH) + (size_t)brow * CH + colg];
      }
    }

    // all-lane parallel poll: lane l covers WG l's slot
    {
      const int target = t + 1;
      while (true) {
        int v = __hip_atomic_load(&slots[myslot], __ATOMIC_RELAXED,
                                  __HIP_MEMORY_SCOPE_AGENT);
        if (__all(v >= target)) break;
      }
    }
    // no release barrier needed: hS/hX hazards covered by S2/S4 +
    // own-slot inclusion in the poll.
  }
}

// ---------------------------------------------------------------------------
extern "C" void kernel_launch(void* const* d_in, const int* in_sizes, int n_in,
                              void* d_out, int out_size, void* d_ws, size_t ws_size,
                              hipStream_t stream)
{
  const float* inputs = (const float*)d_in[0];  // [512,64,512]
  const float* state  = (const float*)d_in[1];  // [1,64,1024]
  const float* Wx     = (const float*)d_in[2];  // [512,1024]
  const float* Wh     = (const float*)d_in[3];  // [1024,1024]
  const float* bias   = (const float*)d_in[4];  // [1024]
  float* out = (float*)d_out;
  float* xpf = out + (size_t)T_STEPS * BATCH * CH;  // out[1] region = xp scratch

  char* ws = (char*)d_ws;
  size_t off = 0;
  unsigned short* WxTh = (unsigned short*)(ws + off); off += (size_t)CH * CIN * 2;  // 1 MB
  unsigned short* WxTl = (unsigned short*)(ws + off); off += (size_t)CH * CIN * 2;  // 1 MB
  unsigned short* WhTi = (unsigned short*)(ws + off); off += (size_t)CH * CH * 4;   // 4 MB interleaved
  unsigned short* h0   = (unsigned short*)(ws + off); off += (size_t)BATCH * CH * 2;
  unsigned short* h1   = (unsigned short*)(ws + off); off += (size_t)BATCH * CH * 2;
  int* slots           = (int*)(ws + off);            off += NWG * 32 * sizeof(int);

  hipMemsetAsync(slots, 0, NWG * 32 * sizeof(int), stream);
  hipLaunchKernelGGL(transpose_cvt_split, dim3(CH / 32, CIN / 32), dim3(256), 0, stream,
                     Wx, WxTh, WxTl, CIN, CH, 0);
  hipLaunchKernelGGL(transpose_cvt_split, dim3(CH / 32, CH / 32), dim3(256), 0, stream,
                     Wh, WhTi, (unsigned short*)nullptr, CH, CH, 1);
  hipLaunchKernelGGL(cvt_f32_bf16, dim3((BATCH * CH / 4) / 256), dim3(256), 0, stream,
                     state, h0, BATCH * CH);
  hipLaunchKernelGGL(gemm_xp, dim3(CH / BN, (T_STEPS * BATCH) / BM), dim3(256), 0, stream,
                     inputs, WxTh, WxTl, bias, xpf);
  hipLaunchKernelGGL(rnn_scan, dim3(NWG), dim3(256), 0, stream,
                     WhTi, xpf, h0, h1, out, slots);
}